// Round 14
// baseline (142.819 us; speedup 1.0000x reference)
//
#include <hip/hip_runtime.h>
#include <hip/hip_bf16.h>

// B=16, T=2048, C=384, H=64. out = softmax((x Wq)(x Wk)^T / sqrt(C)) (x Wv)
// ws (bf16): Qb[32768*64] | Kb[32768*64] | Vt[16][64][2048]   (Wt eliminated)
// R17: pack_w FUSED into qkv_proj's W staging. qkv already stages W into
// LDS per chunk; each thread's (h, c'-block) is fixed, so it loads its 8
// raw f32 W values (stride-64, L2-resident, prefetched in the same slot
// wpre used) and converts in-register -- bit-identical bf16 to pack_w's.
// Removes one dispatch + one serialized launch gap (~4-5 us of the chain).
// flash_attn unchanged from R13/R16 (session best). Noise band established
// at +-1.5-2 us by the R16 re-measure (120.6 vs 122.3 for identical code).

typedef __bf16 bf16;
typedef __attribute__((ext_vector_type(8))) __bf16 bf16x8;
typedef __attribute__((ext_vector_type(4))) __bf16 bf16x4;
typedef __attribute__((ext_vector_type(4))) float f32x4;

#define SCALE_LOG2E (0.051031036307982884f * 1.4426950408889634f)

// swizzled element pointer into a [64][64] bf16 tile (128 B rows):
// byte = row*128 + (cbyte ^ ((row&7)<<4)); bijective, keeps 16B/8B alignment.
__device__ __forceinline__ bf16* tp(bf16* base, int row, int cbyte) {
    return (bf16*)((char*)base + row * 128 + (cbyte ^ ((row & 7) << 4)));
}

// ---------------------------------------------------------------------------
// Kernel 1: QKV projection. 64 rows x 192 cols per block, 512 thr (8 waves).
// Wave wv=(rg<<2)|cg: rows rg*32+rt*16 (rt<2), n-tiles cg*3+j (j<3).
// W staged directly from raw f32 Wq/Wk/Wv (pack_w folded in): thread k-group
// g=tid+k*512 owns LDS Wc[h=g>>3][c'=(g&7)*8 .. +8]; source values
// W[ck*64+c'+j][h&63] (stride-64 f32, L2-hit, prefetched one chunk ahead).
// ---------------------------------------------------------------------------
__global__ __launch_bounds__(512) void qkv_proj(const float* __restrict__ x,
                                                const float* __restrict__ Wq,
                                                const float* __restrict__ Wk,
                                                const float* __restrict__ Wv,
                                                bf16* __restrict__ Qb,
                                                bf16* __restrict__ Kb,
                                                bf16* __restrict__ Vtg) {
    __shared__ __align__(16) bf16 Xs[2][64 * 72];
    __shared__ __align__(16) bf16 Ws[2][192 * 72];

    const int tid = threadIdx.x;
    const int wv = tid >> 6, lane = tid & 63, quad = lane >> 4, l16 = lane & 15;
    const int rg = wv >> 2, cg = wv & 3;
    const int row0 = blockIdx.x * 64;

    // per-k-group W source pointers (h fixed per thread): base for c'=j walk
    const float* wsrc[3];
#pragma unroll
    for (int k = 0; k < 3; k++) {
        int g = tid + k * 512;
        int hh = g >> 3;                       // 0..191
        const float* W = (hh < 64) ? Wq : (hh < 128 ? Wk : Wv);
        wsrc[k] = W + (long)((g & 7) * 8) * 64 + (hh & 63);   // + (ck*64+j)*64
    }

    f32x4 acc[6];                                  // [rt][j] -> acc[rt*3+j]
#pragma unroll
    for (int n = 0; n < 6; n++) acc[n] = (f32x4){0.f, 0.f, 0.f, 0.f};

    float4 xpre[2];
    float wpre[3][8];
#pragma unroll
    for (int k = 0; k < 2; k++) {
        int g = tid + k * 512;
        xpre[k] = *(const float4*)(x + (long)(row0 + (g >> 4)) * 384 + (g & 15) * 4);
    }
#pragma unroll
    for (int k = 0; k < 3; k++)
#pragma unroll
        for (int j = 0; j < 8; j++)
            wpre[k][j] = wsrc[k][j * 64];

    for (int ck = 0; ck < 6; ck++) {
        bf16* Xc = Xs[ck & 1];
        bf16* Wc = Ws[ck & 1];
#pragma unroll
        for (int k = 0; k < 2; k++) {
            int g = tid + k * 512;
            float4 xv = xpre[k];
            *(bf16x4*)(&Xc[(g >> 4) * 72 + (g & 15) * 4]) =
                (bf16x4){(bf16)xv.x, (bf16)xv.y, (bf16)xv.z, (bf16)xv.w};
        }
#pragma unroll
        for (int k = 0; k < 3; k++) {
            int g = tid + k * 512;
            bf16x8 wb;
#pragma unroll
            for (int j = 0; j < 8; j++) wb[j] = (bf16)wpre[k][j];
            *(bf16x8*)(&Wc[(g >> 3) * 72 + (g & 7) * 8]) = wb;
        }
        if (ck < 5) {
#pragma unroll
            for (int k = 0; k < 2; k++) {
                int g = tid + k * 512;
                xpre[k] = *(const float4*)(x + (long)(row0 + (g >> 4)) * 384 +
                                           (ck + 1) * 64 + (g & 15) * 4);
            }
#pragma unroll
            for (int k = 0; k < 3; k++)
#pragma unroll
                for (int j = 0; j < 8; j++)
                    wpre[k][j] = wsrc[k][(long)(ck + 1) * 4096 + j * 64];
        }
        __syncthreads();
#pragma unroll
        for (int kh = 0; kh < 2; kh++) {
            bf16x8 bb[3];
#pragma unroll
            for (int j = 0; j < 3; j++)
                bb[j] = *(bf16x8*)(&Wc[((cg * 3 + j) * 16 + l16) * 72 + kh * 32 + quad * 8]);
#pragma unroll
            for (int rt = 0; rt < 2; rt++) {
                bf16x8 a = *(bf16x8*)(&Xc[(rg * 32 + rt * 16 + l16) * 72 + kh * 32 + quad * 8]);
#pragma unroll
                for (int j = 0; j < 3; j++)
                    acc[rt * 3 + j] = __builtin_amdgcn_mfma_f32_16x16x32_bf16(
                        a, bb[j], acc[rt * 3 + j], 0, 0, 0);
            }
        }
        __syncthreads();        // MFMA reads done before next chunk's commit
    }

    // epilogue: scatter acc (n = cg*3+j wave-uniform) into staging buffers
#pragma unroll
    for (int rt = 0; rt < 2; rt++) {
#pragma unroll
        for (int j = 0; j < 3; j++) {
            const int n = cg * 3 + j;
            const int drow = rg * 32 + rt * 16 + quad * 4;
#pragma unroll
            for (int r = 0; r < 4; r++) {
                float v = acc[rt * 3 + j][r];
                if (n < 4)
                    Xs[0][(drow + r) * 72 + n * 16 + l16] = (bf16)(v * SCALE_LOG2E);
                else if (n < 8)
                    Xs[1][(drow + r) * 72 + (n - 4) * 16 + l16] = (bf16)v;
                else
                    Ws[0][((n - 8) * 16 + l16) * 72 + drow + r] = (bf16)v;
            }
        }
    }
    __syncthreads();
    const int b = row0 >> 11, t0 = row0 & 2047;
    const int srow = tid >> 3, scb = (tid & 7) * 8;
    *(bf16x8*)(Qb + (long)(row0 + srow) * 64 + scb) =
        *(bf16x8*)(&Xs[0][srow * 72 + scb]);
    *(bf16x8*)(Kb + (long)(row0 + srow) * 64 + scb) =
        *(bf16x8*)(&Xs[1][srow * 72 + scb]);
    *(bf16x8*)(Vtg + (long)(b * 64 + srow) * 2048 + t0 + scb) =
        *(bf16x8*)(&Ws[0][srow * 72 + scb]);
}

// ---------------------------------------------------------------------------
// Kernel 2: flash attention (R13/R16 verbatim -- session best).
// 512 blocks x 512 thr (8 waves), 32 k-iters. Waves 0-3 (S): key-subtile;
// K-direct frags; exp2; Ps write; V staging. Waves 4-7 (PV): q-subtile;
// pb/va reads; O/l accumulate. setprio(1) on MFMA clusters.
// LDS 32768 B: Qs/Ps0 @0 | VsA 2x8192 @8192 | Ps1 @24576.
// ---------------------------------------------------------------------------
__global__ __launch_bounds__(512) void flash_attn(const bf16* __restrict__ Qb,
                                                  const bf16* __restrict__ Kb,
                                                  const bf16* __restrict__ Vtg,
                                                  float* __restrict__ out) {
    __shared__ __align__(16) char smem[32768];
    bf16* Qs  = (bf16*)smem;                  // [64][64]; Ps0 overlays after hoist
    bf16* Ps0 = Qs;
    bf16* Ps1 = (bf16*)(smem + 24576);

    const int tid = threadIdx.x;
    const int wv = tid >> 6, lane = tid & 63, quad = lane >> 4, l16 = lane & 15;
    const bool sw = (wv < 4);                 // S/staging waves
    const int pq = wv - 4;                    // PV wave's q-tile
    // XCD-aware swizzle: keep a batch's K/V resident in one XCD's L2.
    const int i0 = blockIdx.x;
    const int b = (i0 & 7) + 8 * ((i0 >> 3) >> 5);
    const int qt = (i0 >> 3) & 31;

    const bf16* Qg = Qb + (long)(b * 2048 + qt * 64) * 64;
    const bf16* Kg = Kb + (long)b * 2048 * 64;
    const bf16* Vg = Vtg + (long)b * 64 * 2048;

    // stage Q tile [64][64] (swizzled): 512 thr x 16B
    const int qrow = tid >> 3, qcb = (tid & 7) * 16;
    *(bf16x8*)tp(Qs, qrow, qcb) = *(const bf16x8*)(Qg + qrow * 64 + (qcb >> 1));

    // V staging geometry (S-waves, tid<256): 256 lanes x 32B
    const int vrow = tid >> 2, vcb = (tid & 3) * 32;
    // K fragment base (S-waves): ka[j]=K[kt*64+wv*16+l16][kh*32+quad*8+j]
    const bf16* Kfb = Kg + (wv * 16 + l16) * 64 + quad * 8;

    bf16x8 kf[2][2], vp[2];
    if (sw) {
        kf[0][0] = *(const bf16x8*)(Kfb);
        kf[0][1] = *(const bf16x8*)(Kfb + 32);
        vp[0] = *(const bf16x8*)(Vg + (long)vrow * 2048 + (vcb >> 1));
        vp[1] = *(const bf16x8*)(Vg + (long)vrow * 2048 + (vcb >> 1) + 8);
    }

    f32x4 o[4], ol;
#pragma unroll
    for (int n = 0; n < 4; n++) o[n] = (f32x4){0.f, 0.f, 0.f, 0.f};
    ol = (f32x4){0.f, 0.f, 0.f, 0.f};

    __syncthreads();            // Qs staged
    // hoist Q^T b-frags (S-waves only; loop-invariant)
    bf16x8 qb[4][2];
    if (sw) {
#pragma unroll
        for (int nt = 0; nt < 4; nt++)
#pragma unroll
            for (int kh = 0; kh < 2; kh++)
                qb[nt][kh] = *(bf16x8*)tp(Qs, nt * 16 + l16, kh * 64 + quad * 16);
    }
    __syncthreads();            // hoist done before Ps0 (=Qs) writes

    const bf16 one = (bf16)1.0f;
    const bf16x8 ones = {one, one, one, one, one, one, one, one};

#pragma unroll 2
    for (int kt = 0; kt < 32; kt++) {
        bf16* Vn = (bf16*)(smem + 8192 + (kt & 1) * 8192);        // commit V[kt]
        bf16* Vp = (bf16*)(smem + 8192 + ((kt + 1) & 1) * 8192);  // PV src: V[kt-1]
        bf16* Pw = (kt & 1) ? Ps1 : Ps0;                          // write Ps[kt]
        bf16* Pr = (kt & 1) ? Ps0 : Ps1;                          // read  Ps[kt-1]

        if (sw) {
            // commit prefetched V tile (region not read this iteration)
            *(bf16x8*)tp(Vn, vrow, vcb)      = vp[0];
            *(bf16x8*)tp(Vn, vrow, vcb + 16) = vp[1];
            // issue next prefetches (stay in flight across the barrier)
            if (kt < 31) {
                kf[(kt + 1) & 1][0] = *(const bf16x8*)(Kfb + (long)(kt + 1) * 4096);
                kf[(kt + 1) & 1][1] = *(const bf16x8*)(Kfb + (long)(kt + 1) * 4096 + 32);
                vp[0] = *(const bf16x8*)(Vg + (long)vrow * 2048 + (kt + 1) * 64 + (vcb >> 1));
                vp[1] = *(const bf16x8*)(Vg + (long)vrow * 2048 + (kt + 1) * 64 + (vcb >> 1) + 8);
            }
            // S^T[kt] = K Q^T : this wave's key subtile (m=wv), all 4 q-tiles
            f32x4 s[4];
#pragma unroll
            for (int nt = 0; nt < 4; nt++) s[nt] = (f32x4){0.f, 0.f, 0.f, 0.f};
            __builtin_amdgcn_s_setprio(1);
#pragma unroll
            for (int kh = 0; kh < 2; kh++) {
                bf16x8 ka = kf[kt & 1][kh];
#pragma unroll
                for (int nt = 0; nt < 4; nt++)
                    s[nt] = __builtin_amdgcn_mfma_f32_16x16x32_bf16(ka, qb[nt][kh], s[nt], 0, 0, 0);
            }
            __builtin_amdgcn_s_setprio(0);
            // p = exp2(s), pack 4 -> b64 store into Ps[kt]
#pragma unroll
            for (int nt = 0; nt < 4; nt++) {
                bf16x4 pp;
#pragma unroll
                for (int r = 0; r < 4; r++)
                    pp[r] = (bf16)__builtin_amdgcn_exp2f(s[nt][r]);
                *(bf16x4*)tp(Pw, nt * 16 + l16, wv * 32 + quad * 8) = pp;
            }
        } else if (kt) {
            // O^T += V[kt-1]^T Ps[kt-1] : this wave's q subtile (n=pq)
            __builtin_amdgcn_s_setprio(1);
#pragma unroll
            for (int kh = 0; kh < 2; kh++) {
                bf16x8 pb = *(bf16x8*)tp(Pr, pq * 16 + l16, kh * 64 + quad * 16);
#pragma unroll
                for (int mt = 0; mt < 4; mt++) {
                    bf16x8 va = *(bf16x8*)tp(Vp, mt * 16 + l16, kh * 64 + quad * 16);
                    o[mt] = __builtin_amdgcn_mfma_f32_16x16x32_bf16(va, pb, o[mt], 0, 0, 0);
                }
                ol = __builtin_amdgcn_mfma_f32_16x16x32_bf16(ones, pb, ol, 0, 0, 0);
            }
            __builtin_amdgcn_s_setprio(0);
        }
        __syncthreads();        // single barrier: publishes V[kt] and Ps[kt]
    }

    // peeled PV[31]: Ps[31] in Ps1, V[31] in parity-1 buffer
    if (!sw) {
        bf16* Pr = Ps1;
        bf16* Vp = (bf16*)(smem + 16384);
#pragma unroll
        for (int kh = 0; kh < 2; kh++) {
            bf16x8 pb = *(bf16x8*)tp(Pr, pq * 16 + l16, kh * 64 + quad * 16);
#pragma unroll
            for (int mt = 0; mt < 4; mt++) {
                bf16x8 va = *(bf16x8*)tp(Vp, mt * 16 + l16, kh * 64 + quad * 16);
                o[mt] = __builtin_amdgcn_mfma_f32_16x16x32_bf16(va, pb, o[mt], 0, 0, 0);
            }
            ol = __builtin_amdgcn_mfma_f32_16x16x32_bf16(ones, pb, ol, 0, 0, 0);
        }
    }

    // epilogue: PV lanes hold l(q) in ol[*]; normalize, transpose via LDS
    float inv = 1.0f / ol[0];
    __syncthreads();            // last loop reads done before Om overlay
    float* Om = (float*)(smem + 8192);        // [64][68] floats (17408 B)
    if (!sw) {
#pragma unroll
        for (int mt = 0; mt < 4; mt++) {
            f32x4 ov;
#pragma unroll
            for (int r = 0; r < 4; r++) ov[r] = o[mt][r] * inv;
            *(f32x4*)(&Om[(pq * 16 + l16) * 68 + mt * 16 + quad * 4]) = ov;
        }
    }
    __syncthreads();
    const int orow = tid >> 3, ocf = (tid & 7) * 8;
    float* og = out + (long)(b * 2048 + qt * 64 + orow) * 64 + ocf;
#pragma unroll
    for (int j = 0; j < 2; j++)
        *(float4*)(og + j * 4) = *(float4*)(&Om[orow * 68 + ocf + j * 4]);
}

// ---------------------------------------------------------------------------
extern "C" void kernel_launch(void* const* d_in, const int* in_sizes, int n_in,
                              void* d_out, int out_size, void* d_ws, size_t ws_size,
                              hipStream_t stream) {
    const float* x  = (const float*)d_in[0];
    const float* Wq = (const float*)d_in[1];
    const float* Wk = (const float*)d_in[2];
    const float* Wv = (const float*)d_in[3];
    float* out = (float*)d_out;

    bf16* Qb  = (bf16*)d_ws;           // 32768*64
    bf16* Kb  = Qb + 2097152;
    bf16* Vtg = Kb + 2097152;          // [16][64][2048]

    qkv_proj<<<512, 512, 0, stream>>>(x, Wq, Wk, Wv, Qb, Kb, Vtg);
    flash_attn<<<512, 512, 0, stream>>>(Qb, Kb, Vtg, out);
}

// Round 15
// 121.498 us; speedup vs baseline: 1.1755x; 1.1755x over previous
//
#include <hip/hip_runtime.h>
#include <hip/hip_bf16.h>

// B=16, T=2048, C=384, H=64. out = softmax((x Wq)(x Wk)^T / sqrt(C)) (x Wv)
// ws (bf16): Qb[32768*64] | Kb[32768*64] | Vt[16][64][2048] | Wt[6*192*64]
// R18: revert R17 (pack_w fusion regressed 122->143 us: the W transpose-
// gather, amortized ONCE by pack_w, was re-executed per-block = 512x as
// 24 scalar stride-256B loads/thread/chunk -> qkv 17->45 us latency wall).
// This is R13/R16 verbatim -- the session's measured best (120.6 us).
// Falsified levers (do not retry): global_load_lds staging (R6), fusion
// w/ grid sync (R3), PV kg-split (R11, VGPR cliff), superstep-2 (R12),
// pack_w fusion (R14/R17), barrier/setprio-only rescheduling (R7/R10).

typedef __bf16 bf16;
typedef __attribute__((ext_vector_type(8))) __bf16 bf16x8;
typedef __attribute__((ext_vector_type(4))) __bf16 bf16x4;
typedef __attribute__((ext_vector_type(4))) float f32x4;

#define SCALE_LOG2E (0.051031036307982884f * 1.4426950408889634f)

// swizzled element pointer into a [64][64] bf16 tile (128 B rows):
// byte = row*128 + (cbyte ^ ((row&7)<<4)); bijective, keeps 16B/8B alignment.
__device__ __forceinline__ bf16* tp(bf16* base, int row, int cbyte) {
    return (bf16*)((char*)base + row * 128 + (cbyte ^ ((row & 7) << 4)));
}

// ---------------------------------------------------------------------------
// Kernel 0: pack W^T, Wt[ck][h][c'] (c = ck*64+c', h in [0,192) = Wq|Wk|Wv).
// ---------------------------------------------------------------------------
__global__ void pack_w(const float* __restrict__ Wq, const float* __restrict__ Wk,
                       const float* __restrict__ Wv, bf16* __restrict__ Wt) {
    int idx = blockIdx.x * 256 + threadIdx.x;      // 0..73727
    int cc = idx & 63;
    int hh = (idx >> 6) % 192;
    int ck = idx / 12288;
    const float* W = (hh < 64) ? Wq : (hh < 128 ? Wk : Wv);
    Wt[idx] = (bf16)W[(ck * 64 + cc) * 64 + (hh & 63)];
}

// ---------------------------------------------------------------------------
// Kernel 1: QKV projection. 64 rows x 192 cols per block, 512 thr (8 waves).
// Wave wv=(rg<<2)|cg: rows rg*32+rt*16 (rt<2), n-tiles cg*3+j (j<3).
// ---------------------------------------------------------------------------
__global__ __launch_bounds__(512) void qkv_proj(const float* __restrict__ x,
                                                const bf16* __restrict__ Wt,
                                                bf16* __restrict__ Qb,
                                                bf16* __restrict__ Kb,
                                                bf16* __restrict__ Vtg) {
    __shared__ __align__(16) bf16 Xs[2][64 * 72];
    __shared__ __align__(16) bf16 Ws[2][192 * 72];

    const int tid = threadIdx.x;
    const int wv = tid >> 6, lane = tid & 63, quad = lane >> 4, l16 = lane & 15;
    const int rg = wv >> 2, cg = wv & 3;
    const int row0 = blockIdx.x * 64;

    f32x4 acc[6];                                  // [rt][j] -> acc[rt*3+j]
#pragma unroll
    for (int n = 0; n < 6; n++) acc[n] = (f32x4){0.f, 0.f, 0.f, 0.f};

    float4 xpre[2];
    bf16x8 wpre[3];
#pragma unroll
    for (int k = 0; k < 2; k++) {
        int g = tid + k * 512;
        xpre[k] = *(const float4*)(x + (long)(row0 + (g >> 4)) * 384 + (g & 15) * 4);
    }
#pragma unroll
    for (int k = 0; k < 3; k++)
        wpre[k] = *(const bf16x8*)(Wt + (tid + k * 512) * 8);

    for (int ck = 0; ck < 6; ck++) {
        bf16* Xc = Xs[ck & 1];
        bf16* Wc = Ws[ck & 1];
#pragma unroll
        for (int k = 0; k < 2; k++) {
            int g = tid + k * 512;
            float4 xv = xpre[k];
            *(bf16x4*)(&Xc[(g >> 4) * 72 + (g & 15) * 4]) =
                (bf16x4){(bf16)xv.x, (bf16)xv.y, (bf16)xv.z, (bf16)xv.w};
        }
#pragma unroll
        for (int k = 0; k < 3; k++) {
            int g = tid + k * 512;
            *(bf16x8*)(&Wc[(g >> 3) * 72 + (g & 7) * 8]) = wpre[k];
        }
        if (ck < 5) {
#pragma unroll
            for (int k = 0; k < 2; k++) {
                int g = tid + k * 512;
                xpre[k] = *(const float4*)(x + (long)(row0 + (g >> 4)) * 384 +
                                           (ck + 1) * 64 + (g & 15) * 4);
            }
#pragma unroll
            for (int k = 0; k < 3; k++)
                wpre[k] = *(const bf16x8*)(Wt + (ck + 1) * 12288 + (tid + k * 512) * 8);
        }
        __syncthreads();
#pragma unroll
        for (int kh = 0; kh < 2; kh++) {
            bf16x8 bb[3];
#pragma unroll
            for (int j = 0; j < 3; j++)
                bb[j] = *(bf16x8*)(&Wc[((cg * 3 + j) * 16 + l16) * 72 + kh * 32 + quad * 8]);
#pragma unroll
            for (int rt = 0; rt < 2; rt++) {
                bf16x8 a = *(bf16x8*)(&Xc[(rg * 32 + rt * 16 + l16) * 72 + kh * 32 + quad * 8]);
#pragma unroll
                for (int j = 0; j < 3; j++)
                    acc[rt * 3 + j] = __builtin_amdgcn_mfma_f32_16x16x32_bf16(
                        a, bb[j], acc[rt * 3 + j], 0, 0, 0);
            }
        }
    }

    // epilogue: scatter acc (n = cg*3+j wave-uniform) into staging buffers
    __syncthreads();
#pragma unroll
    for (int rt = 0; rt < 2; rt++) {
#pragma unroll
        for (int j = 0; j < 3; j++) {
            const int n = cg * 3 + j;
            const int drow = rg * 32 + rt * 16 + quad * 4;
#pragma unroll
            for (int r = 0; r < 4; r++) {
                float v = acc[rt * 3 + j][r];
                if (n < 4)
                    Xs[0][(drow + r) * 72 + n * 16 + l16] = (bf16)(v * SCALE_LOG2E);
                else if (n < 8)
                    Xs[1][(drow + r) * 72 + (n - 4) * 16 + l16] = (bf16)v;
                else
                    Ws[0][((n - 8) * 16 + l16) * 72 + drow + r] = (bf16)v;
            }
        }
    }
    __syncthreads();
    const int b = row0 >> 11, t0 = row0 & 2047;
    const int srow = tid >> 3, scb = (tid & 7) * 8;
    *(bf16x8*)(Qb + (long)(row0 + srow) * 64 + scb) =
        *(bf16x8*)(&Xs[0][srow * 72 + scb]);
    *(bf16x8*)(Kb + (long)(row0 + srow) * 64 + scb) =
        *(bf16x8*)(&Xs[1][srow * 72 + scb]);
    *(bf16x8*)(Vtg + (long)(b * 64 + srow) * 2048 + t0 + scb) =
        *(bf16x8*)(&Ws[0][srow * 72 + scb]);
}

// ---------------------------------------------------------------------------
// Kernel 2: flash attention, 512 blocks x 512 thr (8 waves), 32 k-iters.
// Waves 0-3 (S): key-subtile wv; K-direct frags; exp2; Ps write; V staging.
// Waves 4-7 (PV): q-subtile wv-4; pb/va LDS reads; O/l accumulate.
// s_setprio(1) around both MFMA clusters.
// LDS 32768 B: Qs/Ps0 @0 | VsA 2x8192 @8192 | Ps1 @24576
//   Om [64][68] f32 overlays @8192 (epilogue only, after final barrier).
// Parity: V commit [kt&1] (S), PV reads [(kt+1)&1]=V[kt-1]; Ps write
// [kt&1] (S), PV reads [(kt-1)&1]; kf reg-dbuf under unroll 2.
// ---------------------------------------------------------------------------
__global__ __launch_bounds__(512) void flash_attn(const bf16* __restrict__ Qb,
                                                  const bf16* __restrict__ Kb,
                                                  const bf16* __restrict__ Vtg,
                                                  float* __restrict__ out) {
    __shared__ __align__(16) char smem[32768];
    bf16* Qs  = (bf16*)smem;                  // [64][64]; Ps0 overlays after hoist
    bf16* Ps0 = Qs;
    bf16* Ps1 = (bf16*)(smem + 24576);

    const int tid = threadIdx.x;
    const int wv = tid >> 6, lane = tid & 63, quad = lane >> 4, l16 = lane & 15;
    const bool sw = (wv < 4);                 // S/staging waves
    const int pq = wv - 4;                    // PV wave's q-tile
    // XCD-aware swizzle: keep a batch's K/V resident in one XCD's L2.
    const int i0 = blockIdx.x;
    const int b = (i0 & 7) + 8 * ((i0 >> 3) >> 5);
    const int qt = (i0 >> 3) & 31;

    const bf16* Qg = Qb + (long)(b * 2048 + qt * 64) * 64;
    const bf16* Kg = Kb + (long)b * 2048 * 64;
    const bf16* Vg = Vtg + (long)b * 64 * 2048;

    // stage Q tile [64][64] (swizzled): 512 thr x 16B
    const int qrow = tid >> 3, qcb = (tid & 7) * 16;
    *(bf16x8*)tp(Qs, qrow, qcb) = *(const bf16x8*)(Qg + qrow * 64 + (qcb >> 1));

    // V staging geometry (S-waves, tid<256): 256 lanes x 32B
    const int vrow = tid >> 2, vcb = (tid & 3) * 32;
    // K fragment base (S-waves): ka[j]=K[kt*64+wv*16+l16][kh*32+quad*8+j]
    const bf16* Kfb = Kg + (wv * 16 + l16) * 64 + quad * 8;

    bf16x8 kf[2][2], vp[2];
    if (sw) {
        kf[0][0] = *(const bf16x8*)(Kfb);
        kf[0][1] = *(const bf16x8*)(Kfb + 32);
        vp[0] = *(const bf16x8*)(Vg + (long)vrow * 2048 + (vcb >> 1));
        vp[1] = *(const bf16x8*)(Vg + (long)vrow * 2048 + (vcb >> 1) + 8);
    }

    f32x4 o[4], ol;
#pragma unroll
    for (int n = 0; n < 4; n++) o[n] = (f32x4){0.f, 0.f, 0.f, 0.f};
    ol = (f32x4){0.f, 0.f, 0.f, 0.f};

    __syncthreads();            // Qs staged
    // hoist Q^T b-frags (S-waves only; loop-invariant)
    bf16x8 qb[4][2];
    if (sw) {
#pragma unroll
        for (int nt = 0; nt < 4; nt++)
#pragma unroll
            for (int kh = 0; kh < 2; kh++)
                qb[nt][kh] = *(bf16x8*)tp(Qs, nt * 16 + l16, kh * 64 + quad * 16);
    }
    __syncthreads();            // hoist done before Ps0 (=Qs) writes

    const bf16 one = (bf16)1.0f;
    const bf16x8 ones = {one, one, one, one, one, one, one, one};

#pragma unroll 2
    for (int kt = 0; kt < 32; kt++) {
        bf16* Vn = (bf16*)(smem + 8192 + (kt & 1) * 8192);        // commit V[kt]
        bf16* Vp = (bf16*)(smem + 8192 + ((kt + 1) & 1) * 8192);  // PV src: V[kt-1]
        bf16* Pw = (kt & 1) ? Ps1 : Ps0;                          // write Ps[kt]
        bf16* Pr = (kt & 1) ? Ps0 : Ps1;                          // read  Ps[kt-1]

        if (sw) {
            // commit prefetched V tile (region not read this iteration)
            *(bf16x8*)tp(Vn, vrow, vcb)      = vp[0];
            *(bf16x8*)tp(Vn, vrow, vcb + 16) = vp[1];
            // issue next prefetches (stay in flight across the barrier)
            if (kt < 31) {
                kf[(kt + 1) & 1][0] = *(const bf16x8*)(Kfb + (long)(kt + 1) * 4096);
                kf[(kt + 1) & 1][1] = *(const bf16x8*)(Kfb + (long)(kt + 1) * 4096 + 32);
                vp[0] = *(const bf16x8*)(Vg + (long)vrow * 2048 + (kt + 1) * 64 + (vcb >> 1));
                vp[1] = *(const bf16x8*)(Vg + (long)vrow * 2048 + (kt + 1) * 64 + (vcb >> 1) + 8);
            }
            // S^T[kt] = K Q^T : this wave's key subtile (m=wv), all 4 q-tiles
            f32x4 s[4];
#pragma unroll
            for (int nt = 0; nt < 4; nt++) s[nt] = (f32x4){0.f, 0.f, 0.f, 0.f};
            __builtin_amdgcn_s_setprio(1);
#pragma unroll
            for (int kh = 0; kh < 2; kh++) {
                bf16x8 ka = kf[kt & 1][kh];
#pragma unroll
                for (int nt = 0; nt < 4; nt++)
                    s[nt] = __builtin_amdgcn_mfma_f32_16x16x32_bf16(ka, qb[nt][kh], s[nt], 0, 0, 0);
            }
            __builtin_amdgcn_s_setprio(0);
            // p = exp2(s), pack 4 -> b64 store into Ps[kt]
#pragma unroll
            for (int nt = 0; nt < 4; nt++) {
                bf16x4 pp;
#pragma unroll
                for (int r = 0; r < 4; r++)
                    pp[r] = (bf16)__builtin_amdgcn_exp2f(s[nt][r]);
                *(bf16x4*)tp(Pw, nt * 16 + l16, wv * 32 + quad * 8) = pp;
            }
        } else if (kt) {
            // O^T += V[kt-1]^T Ps[kt-1] : this wave's q subtile (n=pq)
            __builtin_amdgcn_s_setprio(1);
#pragma unroll
            for (int kh = 0; kh < 2; kh++) {
                bf16x8 pb = *(bf16x8*)tp(Pr, pq * 16 + l16, kh * 64 + quad * 16);
#pragma unroll
                for (int mt = 0; mt < 4; mt++) {
                    bf16x8 va = *(bf16x8*)tp(Vp, mt * 16 + l16, kh * 64 + quad * 16);
                    o[mt] = __builtin_amdgcn_mfma_f32_16x16x32_bf16(va, pb, o[mt], 0, 0, 0);
                }
                ol = __builtin_amdgcn_mfma_f32_16x16x32_bf16(ones, pb, ol, 0, 0, 0);
            }
            __builtin_amdgcn_s_setprio(0);
        }
        __syncthreads();        // single barrier: publishes V[kt] and Ps[kt]
    }

    // peeled PV[31]: Ps[31] in Ps1, V[31] in parity-1 buffer
    if (!sw) {
        bf16* Pr = Ps1;
        bf16* Vp = (bf16*)(smem + 16384);
#pragma unroll
        for (int kh = 0; kh < 2; kh++) {
            bf16x8 pb = *(bf16x8*)tp(Pr, pq * 16 + l16, kh * 64 + quad * 16);
#pragma unroll
            for (int mt = 0; mt < 4; mt++) {
                bf16x8 va = *(bf16x8*)tp(Vp, mt * 16 + l16, kh * 64 + quad * 16);
                o[mt] = __builtin_amdgcn_mfma_f32_16x16x32_bf16(va, pb, o[mt], 0, 0, 0);
            }
            ol = __builtin_amdgcn_mfma_f32_16x16x32_bf16(ones, pb, ol, 0, 0, 0);
        }
    }

    // epilogue: PV lanes hold l(q) in ol[*]; normalize, transpose via LDS
    float inv = 1.0f / ol[0];
    __syncthreads();            // last loop reads done before Om overlay
    float* Om = (float*)(smem + 8192);        // [64][68] floats (17408 B)
    if (!sw) {
#pragma unroll
        for (int mt = 0; mt < 4; mt++) {
            f32x4 ov;
#pragma unroll
            for (int r = 0; r < 4; r++) ov[r] = o[mt][r] * inv;
            *(f32x4*)(&Om[(pq * 16 + l16) * 68 + mt * 16 + quad * 4]) = ov;
        }
    }
    __syncthreads();
    const int orow = tid >> 3, ocf = (tid & 7) * 8;
    float* og = out + (long)(b * 2048 + qt * 64 + orow) * 64 + ocf;
#pragma unroll
    for (int j = 0; j < 2; j++)
        *(float4*)(og + j * 4) = *(float4*)(&Om[orow * 68 + ocf + j * 4]);
}

// ---------------------------------------------------------------------------
extern "C" void kernel_launch(void* const* d_in, const int* in_sizes, int n_in,
                              void* d_out, int out_size, void* d_ws, size_t ws_size,
                              hipStream_t stream) {
    const float* x  = (const float*)d_in[0];
    const float* Wq = (const float*)d_in[1];
    const float* Wk = (const float*)d_in[2];
    const float* Wv = (const float*)d_in[3];
    float* out = (float*)d_out;

    bf16* Qb  = (bf16*)d_ws;           // 32768*64
    bf16* Kb  = Qb + 2097152;
    bf16* Vtg = Kb + 2097152;          // [16][64][2048]
    bf16* Wt  = Vtg + 2097152;         // 6*192*64

    pack_w<<<288, 256, 0, stream>>>(Wq, Wk, Wv, Wt);
    qkv_proj<<<512, 512, 0, stream>>>(x, Wt, Qb, Kb, Vtg);
    flash_attn<<<512, 512, 0, stream>>>(Qb, Kb, Vtg, out);
}